// Round 8
// baseline (2312.449 us; speedup 1.0000x reference)
//
#include <hip/hip_runtime.h>

#define NN 4096
#define DD 64
#define NBLK 512      // 256 f-blocks + 256 g-blocks (role = blk>>8)
#define NTHR 1024
#define NWAVE 16
#define ITERS 50

typedef __attribute__((ext_vector_type(8))) short short8;
typedef __attribute__((ext_vector_type(4))) float f32x4;
typedef _Float16 half2v __attribute__((ext_vector_type(2)));
typedef unsigned uintv16 __attribute__((ext_vector_type(16)));
typedef unsigned long long u64;

#define C2f     0.4808983469629878f   /* 1/(eps*ln2), eps=3 */
#define EPSLN2f 2.0794415416798359f   /* eps*ln2 */
#define EPSLNNf 24.95329850015803f    /* eps*ln(4096) */

#define LLC_LD64(p)    __hip_atomic_load((p), __ATOMIC_RELAXED, __HIP_MEMORY_SCOPE_AGENT)
#define LLC_ST64(p, v) __hip_atomic_store((p), (v), __ATOMIC_RELAXED, __HIP_MEMORY_SCOPE_AGENT)

__device__ inline short bf16_of(float f) {
  unsigned u = __float_as_uint(f);
  u += 0x7fffu + ((u >> 16) & 1u);   // RTNE, inputs finite
  return (short)(u >> 16);
}

__device__ inline void pollbar(unsigned* bar, unsigned target) {
  while (__hip_atomic_load(bar, __ATOMIC_RELAXED, __HIP_MEMORY_SCOPE_AGENT) < target)
    __builtin_amdgcn_s_sleep(2);
}
__device__ inline void arrive(unsigned* cnt, int grp, unsigned* bar, unsigned phase) {
  unsigned old = atomicAdd(&cnt[grp << 5], 1u);
  if (old == (phase << 5) - 1u) atomicAdd(bar, 1u);
}

__global__ __launch_bounds__(NTHR, 8)   // 2 blocks/CU resident -> hard 64-VGPR cap
void sink_kernel(const float* __restrict__ X,
                 const float* __restrict__ Y,
                 float* __restrict__ out,
                 unsigned char* __restrict__ ws) {
  unsigned* barI = (unsigned*)ws;             // one-time init barrier
  unsigned* cntI = (unsigned*)(ws + 512);     // 16 groups x 128B
  u64* bGt = (u64*)(ws + 8192);               // tagged g-bias: (phase<<32)|float_bits
  u64* bFt = (u64*)(ws + 49152);              // tagged f-bias
  short* Xb = (short*)(ws + 131072);          // 4096x64 bf16
  short* Yb = Xb + NN * DD;

  const int tid  = threadIdx.x;
  const int blk  = blockIdx.x;
  const int role = blk >> 8;                  // 0 = f-rows, 1 = g-rows
  const int rb   = blk & 255;
  const int wave = tid >> 6;
  const int lane = tid & 63;
  const int i0   = rb << 4;
  const int c0   = (wave << 4) + (lane & 15); // this thread's slot (mod 256)

  __shared__ uint2 shi[8][NTHR];              // S tiles k=8..15 (64 KB)
  __shared__ float red[NWAVE * 16];
  __shared__ float sh_sq[16];

  const float* src = role ? Y : X;
  short* dst = role ? Yb : Xb;

  // ---- init: convert own 16 rows + row norms ----
  dst[rb * NTHR + tid] = bf16_of(src[rb * NTHR + tid]);
  {
    const int row = i0 + wave;
    float v = src[row * DD + lane];
    float s = v * v;
#pragma unroll
    for (int o = 1; o < 64; o <<= 1) s += __shfl_xor(s, o);
    if (lane == 0) sh_sq[wave] = 0.5f * s;
  }
  __syncthreads();
  if (tid == 0) {                             // one-time fenced barrier for Xb/Yb
    __threadfence();
    arrive(cntI, blk >> 5, barI, 1);
    pollbar(barI, 16u);
  }
  __syncthreads();

  // initial g-bias (g0=0), tag 1 — published before build so f never waits on g's build
  if (role == 1 && tid < 16) {
    const float bc = -sh_sq[tid] * C2f;
    LLC_ST64(bGt + i0 + tid, ((u64)1 << 32) | (u64)__float_as_uint(bc));
  }

  // ---- build S = own 16 rows x all 4096 opposite rows (f16): k<8 regs, k>=8 LDS ----
  const short* Ab = role ? Yb : Xb;
  const short* Bb = role ? Xb : Yb;
  const short* ap = Ab + ((i0 + (lane & 15)) << 6) + ((lane >> 4) << 3);
  short8 a0 = *(const short8*)ap;
  short8 a1 = *(const short8*)(ap + 32);
  uintv16 S0;
#pragma unroll
  for (int k = 0; k < 16; ++k) {
    const int jb = (wave << 4) + (k << 8);
    const short* bp = Bb + ((jb + (lane & 15)) << 6) + ((lane >> 4) << 3);
    short8 b0 = *(const short8*)bp;
    short8 b1 = *(const short8*)(bp + 32);
    f32x4 acc = {0.f, 0.f, 0.f, 0.f};
    acc = __builtin_amdgcn_mfma_f32_16x16x32_bf16(a0, b0, acc, 0, 0, 0);
    acc = __builtin_amdgcn_mfma_f32_16x16x32_bf16(a1, b1, acc, 0, 0, 0);
    const unsigned w0 = __builtin_bit_cast(unsigned, __builtin_amdgcn_cvt_pkrtz(acc[0], acc[1]));
    const unsigned w1 = __builtin_bit_cast(unsigned, __builtin_amdgcn_cvt_pkrtz(acc[2], acc[3]));
    if (k < 8) { S0[2 * k] = w0; S0[2 * k + 1] = w1; }
    else       { shi[k - 8][tid] = make_uint2(w0, w1); }
  }

  u64* inb  = role ? bFt : bGt;
  u64* outb = role ? bGt : bFt;
  float* potOut = out + (role ? NN : 0);

  // tag protocol (monotonic, never reused per buffer):
  //   bGt: initial=1, g_it output = it+2.   bFt: f_it output = it+1.
  //   f at it polls bGt for it+1; g at it polls bFt for it+1.
  for (int it = 0; it < ITERS; ++it) {
    const unsigned tagIn  = (unsigned)(it + 1);
    const unsigned tagOut = (unsigned)(role ? it + 2 : it + 1);

    u64 v[16];
#pragma unroll
    for (int k = 0; k < 16; ++k) v[k] = LLC_LD64(inb + c0 + (k << 8));

    float sum[4] = {0.f, 0.f, 0.f, 0.f};
#pragma unroll
    for (int k = 0; k < 16; ++k) {
      while ((unsigned)(v[k] >> 32) != tagIn) {
        __builtin_amdgcn_s_sleep(1);
        v[k] = LLC_LD64(inb + c0 + (k << 8));
      }
      const float bb = __uint_as_float((unsigned)v[k]);
      unsigned w0, w1;
      if (k < 8) { w0 = S0[2 * k]; w1 = S0[2 * k + 1]; }
      else       { const uint2 w = shi[k - 8][tid]; w0 = w.x; w1 = w.y; }
      half2v lo = __builtin_bit_cast(half2v, w0);
      half2v hi = __builtin_bit_cast(half2v, w1);
      sum[0] += __builtin_amdgcn_exp2f(__builtin_fmaf((float)lo[0], C2f, bb));
      sum[1] += __builtin_amdgcn_exp2f(__builtin_fmaf((float)lo[1], C2f, bb));
      sum[2] += __builtin_amdgcn_exp2f(__builtin_fmaf((float)hi[0], C2f, bb));
      sum[3] += __builtin_amdgcn_exp2f(__builtin_fmaf((float)hi[1], C2f, bb));
    }
#pragma unroll
    for (int o = 1; o <= 8; o <<= 1)
#pragma unroll
      for (int r = 0; r < 4; ++r) sum[r] += __shfl_xor(sum[r], o);
    if ((lane & 15) == 0)
#pragma unroll
      for (int r = 0; r < 4; ++r) red[wave * 16 + ((lane >> 4) << 2) + r] = sum[r];
    __syncthreads();                           // red writes visible to wave 0
    if (tid < 16) {
      float total = 0.f;
#pragma unroll
      for (int w = 0; w < NWAVE; ++w) total += red[w * 16 + tid];
      const float pot = sh_sq[tid] - EPSLN2f * __builtin_amdgcn_logf(total) + EPSLNNf;
      if (it == ITERS - 1) potOut[i0 + tid] = pot;
      const float bc = (pot - sh_sq[tid]) * C2f;
      LLC_ST64(outb + i0 + tid, ((u64)tagOut << 32) | (u64)__float_as_uint(bc));
    }
    __syncthreads();                           // protect red against next-iter writes
  }
}

extern "C" void kernel_launch(void* const* d_in, const int* in_sizes, int n_in,
                              void* d_out, int out_size, void* d_ws, size_t ws_size,
                              hipStream_t stream) {
  const float* X = (const float*)d_in[0];
  const float* Y = (const float*)d_in[1];
  float* out = (float*)d_out;
  unsigned char* ws = (unsigned char*)d_ws;
  // zero init-barrier counters + both tagged-bias arrays (tag 0 = never-ready)
  hipMemsetAsync(d_ws, 0, 131072, stream);
  sink_kernel<<<dim3(NBLK), dim3(NTHR), 0, stream>>>(X, Y, out, ws);
}

// Round 9
// 1435.581 us; speedup vs baseline: 1.6108x; 1.6108x over previous
//
#include <hip/hip_runtime.h>

#define NN 4096
#define DD 64
#define NBLK 512      // 256 f-blocks + 256 g-blocks (role = blk>>8)
#define NTHR 1024
#define NWAVE 16
#define ITERS 50

typedef __attribute__((ext_vector_type(8))) short short8;
typedef __attribute__((ext_vector_type(4))) float f32x4;
typedef _Float16 half2v __attribute__((ext_vector_type(2)));
typedef unsigned uintv16 __attribute__((ext_vector_type(16)));

#define C2f     0.4808983469629878f   /* 1/(eps*ln2), eps=3 */
#define EPSLN2f 2.0794415416798359f   /* eps*ln2 */
#define EPSLNNf 24.95329850015803f    /* eps*ln(4096) */

#define LLC_LDU(p)    __hip_atomic_load((p), __ATOMIC_RELAXED, __HIP_MEMORY_SCOPE_AGENT)
#define LLC_STU(p, v) __hip_atomic_store((p), (v), __ATOMIC_RELAXED, __HIP_MEMORY_SCOPE_AGENT)

__device__ inline short bf16_of(float f) {
  unsigned u = __float_as_uint(f);
  u += 0x7fffu + ((u >> 16) & 1u);   // RTNE, inputs finite
  return (short)(u >> 16);
}

__device__ inline void pollbar(unsigned* bar, unsigned target) {
  while (__hip_atomic_load(bar, __ATOMIC_RELAXED, __HIP_MEMORY_SCOPE_AGENT) < target)
    __builtin_amdgcn_s_sleep(2);
}
__device__ inline void arrive(unsigned* cnt, int grp, unsigned* bar, unsigned phase) {
  unsigned old = atomicAdd(&cnt[grp << 5], 1u);
  if (old == (phase << 5) - 1u) atomicAdd(bar, 1u);
}

// publish-index -> tag in {1,2,3}; 0 (memset state) never matches, and publishes
// h, h+2, h+4 to one buffer have pairwise-distinct tags mod 3 (skew <= 2 by dataflow).
__device__ inline unsigned tag_of(int h) { return (unsigned)(h % 3) + 1u; }

__global__ __launch_bounds__(NTHR, 8)   // 2 blocks/CU resident
void sink_kernel(const float* __restrict__ X,
                 const float* __restrict__ Y,
                 float* __restrict__ out,
                 unsigned char* __restrict__ ws) {
  unsigned* barI = (unsigned*)ws;             // one-time init barrier
  unsigned* cntI = (unsigned*)(ws + 512);     // 16 groups x 128B
  unsigned* bGt  = (unsigned*)(ws + 8192);    // tagged g-bias (tag in low 2 bits)
  unsigned* bFt  = (unsigned*)(ws + 24576);   // tagged f-bias
  short* Xb = (short*)(ws + 65536);           // 4096x64 bf16
  short* Yb = Xb + NN * DD;

  const int tid  = threadIdx.x;
  const int blk  = blockIdx.x;
  const int role = blk >> 8;                  // 0 = f-rows, 1 = g-rows
  const int rb   = blk & 255;
  const int wave = tid >> 6;
  const int lane = tid & 63;
  const int i0   = rb << 4;
  const int c0   = (wave << 4) + (lane & 15); // this thread's slot (mod 256)

  __shared__ uint2 shi[8][NTHR];              // S tiles k=8..15 (64 KB)
  __shared__ float red[NWAVE * 16];
  __shared__ float sh_sq[16];

  const float* src = role ? Y : X;
  short* dst = role ? Yb : Xb;

  // ---- init: convert own 16 rows + row norms ----
  dst[rb * NTHR + tid] = bf16_of(src[rb * NTHR + tid]);
  {
    const int row = i0 + wave;
    float v = src[row * DD + lane];
    float s = v * v;
#pragma unroll
    for (int o = 1; o < 64; o <<= 1) s += __shfl_xor(s, o);
    if (lane == 0) sh_sq[wave] = 0.5f * s;
  }
  __syncthreads();
  if (tid == 0) {                             // one-time fenced barrier for Xb/Yb
    __threadfence();
    arrive(cntI, blk >> 5, barI, 1);
    pollbar(barI, 16u);
  }
  __syncthreads();

  // initial g-bias (g0=0), publish index h=0 -> tag 1; before build so f never waits
  if (role == 1 && tid < 16) {
    const float bc = -sh_sq[tid] * C2f;
    LLC_STU(bGt + i0 + tid, (__float_as_uint(bc) & ~3u) | tag_of(0));
  }

  // ---- build S = own 16 rows x all 4096 opposite rows (f16): k<8 regs, k>=8 LDS ----
  const short* Ab = role ? Yb : Xb;
  const short* Bb = role ? Xb : Yb;
  const short* ap = Ab + ((i0 + (lane & 15)) << 6) + ((lane >> 4) << 3);
  short8 a0 = *(const short8*)ap;
  short8 a1 = *(const short8*)(ap + 32);
  uintv16 S0;
#pragma unroll
  for (int k = 0; k < 16; ++k) {
    const int jb = (wave << 4) + (k << 8);
    const short* bp = Bb + ((jb + (lane & 15)) << 6) + ((lane >> 4) << 3);
    short8 b0 = *(const short8*)bp;
    short8 b1 = *(const short8*)(bp + 32);
    f32x4 acc = {0.f, 0.f, 0.f, 0.f};
    acc = __builtin_amdgcn_mfma_f32_16x16x32_bf16(a0, b0, acc, 0, 0, 0);
    acc = __builtin_amdgcn_mfma_f32_16x16x32_bf16(a1, b1, acc, 0, 0, 0);
    const unsigned w0 = __builtin_bit_cast(unsigned, __builtin_amdgcn_cvt_pkrtz(acc[0], acc[1]));
    const unsigned w1 = __builtin_bit_cast(unsigned, __builtin_amdgcn_cvt_pkrtz(acc[2], acc[3]));
    if (k < 8) { S0[2 * k] = w0; S0[2 * k + 1] = w1; }
    else       { shi[k - 8][tid] = make_uint2(w0, w1); }
  }

  unsigned* inb  = role ? bFt : bGt;
  unsigned* outb = role ? bGt : bFt;
  float* potOut = out + (role ? NN : 0);

  // publish indices: bGt gets h=0 (init), h=2it+2 (g_it); bFt gets h=2it+1 (f_it).
  // f at it consumes bGt h=2it; g at it consumes bFt h=2it+1.
  for (int it = 0; it < ITERS; ++it) {
    const unsigned tagIn  = tag_of(role ? 2 * it + 1 : 2 * it);
    const unsigned tagOut = tag_of(role ? 2 * it + 2 : 2 * it + 1);

    unsigned v[16];
#pragma unroll
    for (int k = 0; k < 16; ++k) v[k] = LLC_LDU(inb + c0 + (k << 8));

    float sum[4] = {0.f, 0.f, 0.f, 0.f};
#pragma unroll
    for (int k = 0; k < 16; ++k) {
      while ((v[k] & 3u) != tagIn) {
        __builtin_amdgcn_s_sleep(1);
        v[k] = LLC_LDU(inb + c0 + (k << 8));
      }
      const float bb = __uint_as_float(v[k]);   // tag bits = ~3ulp noise, negligible
      unsigned w0, w1;
      if (k < 8) { w0 = S0[2 * k]; w1 = S0[2 * k + 1]; }
      else       { const uint2 w = shi[k - 8][tid]; w0 = w.x; w1 = w.y; }
      half2v lo = __builtin_bit_cast(half2v, w0);
      half2v hi = __builtin_bit_cast(half2v, w1);
      sum[0] += __builtin_amdgcn_exp2f(__builtin_fmaf((float)lo[0], C2f, bb));
      sum[1] += __builtin_amdgcn_exp2f(__builtin_fmaf((float)lo[1], C2f, bb));
      sum[2] += __builtin_amdgcn_exp2f(__builtin_fmaf((float)hi[0], C2f, bb));
      sum[3] += __builtin_amdgcn_exp2f(__builtin_fmaf((float)hi[1], C2f, bb));
    }
#pragma unroll
    for (int o = 1; o <= 8; o <<= 1)
#pragma unroll
      for (int r = 0; r < 4; ++r) sum[r] += __shfl_xor(sum[r], o);
    if ((lane & 15) == 0)
#pragma unroll
      for (int r = 0; r < 4; ++r) red[wave * 16 + ((lane >> 4) << 2) + r] = sum[r];
    __syncthreads();
    if (tid < 16) {
      float total = 0.f;
#pragma unroll
      for (int w = 0; w < NWAVE; ++w) total += red[w * 16 + tid];
      const float pot = sh_sq[tid] - EPSLN2f * __builtin_amdgcn_logf(total) + EPSLNNf;
      if (it == ITERS - 1) potOut[i0 + tid] = pot;
      const float bc = (pot - sh_sq[tid]) * C2f;
      LLC_STU(outb + i0 + tid, (__float_as_uint(bc) & ~3u) | tagOut);
    }
    __syncthreads();                           // protect red against next-iter writes
  }
}

extern "C" void kernel_launch(void* const* d_in, const int* in_sizes, int n_in,
                              void* d_out, int out_size, void* d_ws, size_t ws_size,
                              hipStream_t stream) {
  const float* X = (const float*)d_in[0];
  const float* Y = (const float*)d_in[1];
  float* out = (float*)d_out;
  unsigned char* ws = (unsigned char*)d_ws;
  // zero init-barrier counters + both tagged-bias arrays (tag 0 = never-ready)
  hipMemsetAsync(d_ws, 0, 65536, stream);
  sink_kernel<<<dim3(NBLK), dim3(NTHR), 0, stream>>>(X, Y, out, ws);
}

// Round 10
// 1208.533 us; speedup vs baseline: 1.9134x; 1.1879x over previous
//
#include <hip/hip_runtime.h>

#define NN 4096
#define DD 64
#define NBLK 512      // 256 f-blocks + 256 g-blocks (role = blk>>8)
#define NTHR 1024
#define NWAVE 16
#define ITERS 50

typedef __attribute__((ext_vector_type(8))) short short8;
typedef __attribute__((ext_vector_type(4))) float f32x4;
typedef _Float16 half2v __attribute__((ext_vector_type(2)));
typedef unsigned uintv16 __attribute__((ext_vector_type(16)));

#define C2f     0.4808983469629878f   /* 1/(eps*ln2), eps=3 */
#define EPSLN2f 2.0794415416798359f   /* eps*ln2 */
#define EPSLNNf 24.95329850015803f    /* eps*ln(4096) */

#define LLC_LDU(p)    __hip_atomic_load((p), __ATOMIC_RELAXED, __HIP_MEMORY_SCOPE_AGENT)
#define LLC_STU(p, v) __hip_atomic_store((p), (v), __ATOMIC_RELAXED, __HIP_MEMORY_SCOPE_AGENT)

__device__ inline short bf16_of(float f) {
  unsigned u = __float_as_uint(f);
  u += 0x7fffu + ((u >> 16) & 1u);   // RTNE, inputs finite
  return (short)(u >> 16);
}

__device__ inline void pollbar(unsigned* bar, unsigned target) {
  while (__hip_atomic_load(bar, __ATOMIC_RELAXED, __HIP_MEMORY_SCOPE_AGENT) < target)
    __builtin_amdgcn_s_sleep(2);
}
__device__ inline void arrive(unsigned* cnt, int grp, unsigned* bar, unsigned phase) {
  unsigned old = atomicAdd(&cnt[grp << 5], 1u);
  if (old == (phase << 5) - 1u) atomicAdd(bar, 1u);
}

// publish-index -> tag in {1,2,3}; 0 (memset state) never matches; successive
// publishes to one buffer differ by 2 -> distinct mod 3 (skew <= 1 by dataflow).
__device__ inline unsigned tag_of(int h) { return (unsigned)(h % 3) + 1u; }

__global__ __launch_bounds__(NTHR, 8)   // 2 blocks/CU resident (deadlock-free)
void sink_kernel(const float* __restrict__ X,
                 const float* __restrict__ Y,
                 float* __restrict__ out,
                 unsigned char* __restrict__ ws) {
  unsigned* barI = (unsigned*)ws;             // one-time init barrier
  unsigned* cntI = (unsigned*)(ws + 512);     // 16 groups x 128B
  unsigned* bGt  = (unsigned*)(ws + 8192);    // tagged g-bias (tag in low 2 bits)
  unsigned* bFt  = (unsigned*)(ws + 24576);   // tagged f-bias
  short* Xb = (short*)(ws + 65536);           // 4096x64 bf16
  short* Yb = Xb + NN * DD;

  const int tid  = threadIdx.x;
  const int blk  = blockIdx.x;
  const int role = blk >> 8;                  // 0 = f-rows, 1 = g-rows
  const int rb   = blk & 255;
  const int wave = tid >> 6;
  const int lane = tid & 63;
  const int i0   = rb << 4;
  const int c0   = (wave << 4) + (lane & 15); // this thread's column slot (mod 256)

  __shared__ uint2 shi[7][NTHR];              // S tiles k=9..15 (56 KB)
  __shared__ unsigned bias_lds[NN];           // staged tagged bias (16 KB)
  __shared__ float red[NWAVE * 16];
  __shared__ float sh_sq[16];

  const float* src = role ? Y : X;
  short* dst = role ? Yb : Xb;

  // ---- init: convert own 16 rows + row norms ----
  dst[rb * NTHR + tid] = bf16_of(src[rb * NTHR + tid]);
  {
    const int row = i0 + wave;
    float v = src[row * DD + lane];
    float s = v * v;
#pragma unroll
    for (int o = 1; o < 64; o <<= 1) s += __shfl_xor(s, o);
    if (lane == 0) sh_sq[wave] = 0.5f * s;
  }
  __syncthreads();
  if (tid == 0) {                             // one-time fenced barrier for Xb/Yb
    __threadfence();
    arrive(cntI, blk >> 5, barI, 1);
    pollbar(barI, 16u);
  }
  __syncthreads();

  // initial g-bias (g0=0), publish index h=0 -> tag 1; before build so f never waits
  if (role == 1 && tid < 16) {
    const float bc = -sh_sq[tid] * C2f;
    LLC_STU(bGt + i0 + tid, (__float_as_uint(bc) & ~3u) | tag_of(0));
  }

  // ---- build S = own 16 rows x all 4096 opposite rows (f16):
  //      tiles k=0..8 in registers (18 dwords), k=9..15 in LDS ----
  const short* Ab = role ? Yb : Xb;
  const short* Bb = role ? Xb : Yb;
  const short* ap = Ab + ((i0 + (lane & 15)) << 6) + ((lane >> 4) << 3);
  short8 a0 = *(const short8*)ap;
  short8 a1 = *(const short8*)(ap + 32);
  uintv16 S0;
  uint2 S8;
#pragma unroll
  for (int k = 0; k < 16; ++k) {
    const int jb = (wave << 4) + (k << 8);
    const short* bp = Bb + ((jb + (lane & 15)) << 6) + ((lane >> 4) << 3);
    short8 b0 = *(const short8*)bp;
    short8 b1 = *(const short8*)(bp + 32);
    f32x4 acc = {0.f, 0.f, 0.f, 0.f};
    acc = __builtin_amdgcn_mfma_f32_16x16x32_bf16(a0, b0, acc, 0, 0, 0);
    acc = __builtin_amdgcn_mfma_f32_16x16x32_bf16(a1, b1, acc, 0, 0, 0);
    const unsigned w0 = __builtin_bit_cast(unsigned, __builtin_amdgcn_cvt_pkrtz(acc[0], acc[1]));
    const unsigned w1 = __builtin_bit_cast(unsigned, __builtin_amdgcn_cvt_pkrtz(acc[2], acc[3]));
    if (k < 8)       { S0[2 * k] = w0; S0[2 * k + 1] = w1; }
    else if (k == 8) { S8.x = w0; S8.y = w1; }
    else             { shi[k - 9][tid] = make_uint2(w0, w1); }
  }

  unsigned* inb  = role ? bFt : bGt;
  unsigned* outb = role ? bGt : bFt;
  float* potOut = out + (role ? NN : 0);

  // publish indices: bGt gets h=0 (init), h=2it+2 (g_it); bFt gets h=2it+1 (f_it).
  // f at it consumes bGt h=2it; g at it consumes bFt h=2it+1.
  for (int it = 0; it < ITERS; ++it) {
    const unsigned tagIn  = tag_of(role ? 2 * it + 1 : 2 * it);
    const unsigned tagOut = tag_of(role ? 2 * it + 2 : 2 * it + 1);

    // ---- fused poll+stage: 4 slots/thread, readiness check IS the bias load ----
    unsigned v[4];
#pragma unroll
    for (int q = 0; q < 4; ++q) v[q] = LLC_LDU(inb + tid + (q << 10));
#pragma unroll
    for (int q = 0; q < 4; ++q) {
      while ((v[q] & 3u) != tagIn) {
        __builtin_amdgcn_s_sleep(1);
        v[q] = LLC_LDU(inb + tid + (q << 10));
      }
      bias_lds[tid + (q << 10)] = v[q];
    }
    __syncthreads();

    float sum[4] = {0.f, 0.f, 0.f, 0.f};
#pragma unroll
    for (int k = 0; k < 16; ++k) {
      const float bb = __uint_as_float(bias_lds[c0 + (k << 8)]); // tag bits ~3ulp noise
      unsigned w0, w1;
      if (k < 8)       { w0 = S0[2 * k]; w1 = S0[2 * k + 1]; }
      else if (k == 8) { w0 = S8.x; w1 = S8.y; }
      else             { const uint2 w = shi[k - 9][tid]; w0 = w.x; w1 = w.y; }
      half2v lo = __builtin_bit_cast(half2v, w0);
      half2v hi = __builtin_bit_cast(half2v, w1);
      sum[0] += __builtin_amdgcn_exp2f(__builtin_fmaf((float)lo[0], C2f, bb));
      sum[1] += __builtin_amdgcn_exp2f(__builtin_fmaf((float)lo[1], C2f, bb));
      sum[2] += __builtin_amdgcn_exp2f(__builtin_fmaf((float)hi[0], C2f, bb));
      sum[3] += __builtin_amdgcn_exp2f(__builtin_fmaf((float)hi[1], C2f, bb));
    }
#pragma unroll
    for (int o = 1; o <= 8; o <<= 1)
#pragma unroll
      for (int r = 0; r < 4; ++r) sum[r] += __shfl_xor(sum[r], o);
    if ((lane & 15) == 0)
#pragma unroll
      for (int r = 0; r < 4; ++r) red[wave * 16 + ((lane >> 4) << 2) + r] = sum[r];
    __syncthreads();
    if (tid < 16) {
      float total = 0.f;
#pragma unroll
      for (int w = 0; w < NWAVE; ++w) total += red[w * 16 + tid];
      const float pot = sh_sq[tid] - EPSLN2f * __builtin_amdgcn_logf(total) + EPSLNNf;
      if (it == ITERS - 1) potOut[i0 + tid] = pot;
      const float bc = (pot - sh_sq[tid]) * C2f;
      LLC_STU(outb + i0 + tid, (__float_as_uint(bc) & ~3u) | tagOut);
    }
    __syncthreads();   // protect red/bias_lds against next-iteration writes
  }
}

extern "C" void kernel_launch(void* const* d_in, const int* in_sizes, int n_in,
                              void* d_out, int out_size, void* d_ws, size_t ws_size,
                              hipStream_t stream) {
  const float* X = (const float*)d_in[0];
  const float* Y = (const float*)d_in[1];
  float* out = (float*)d_out;
  unsigned char* ws = (unsigned char*)d_ws;
  // zero init-barrier counters + both tagged-bias arrays (tag 0 = never-ready)
  hipMemsetAsync(d_ws, 0, 65536, stream);
  sink_kernel<<<dim3(NBLK), dim3(NTHR), 0, stream>>>(X, Y, out, ws);
}

// Round 11
// 493.504 us; speedup vs baseline: 4.6858x; 2.4489x over previous
//
#include <hip/hip_runtime.h>

#define NN 4096
#define DD 64
#define NBLK 256      // merged roles: block b owns f-rows and g-rows [16b, 16b+16)
#define NTHR 1024
#define NWAVE 16
#define ITERS 50

typedef __attribute__((ext_vector_type(8))) short short8;
typedef __attribute__((ext_vector_type(4))) float f32x4;
typedef _Float16 half2v __attribute__((ext_vector_type(2)));

#define C2f     0.4808983469629878f   /* 1/(eps*ln2), eps=3 */
#define EPSLN2f 2.0794415416798359f   /* eps*ln2 */
#define EPSLNNf 24.95329850015803f    /* eps*ln(4096) */

#define LLC_LDU(p)    __hip_atomic_load((p), __ATOMIC_RELAXED, __HIP_MEMORY_SCOPE_AGENT)
#define LLC_STU(p, v) __hip_atomic_store((p), (v), __ATOMIC_RELAXED, __HIP_MEMORY_SCOPE_AGENT)

__device__ inline short bf16_of(float f) {
  unsigned u = __float_as_uint(f);
  u += 0x7fffu + ((u >> 16) & 1u);   // RTNE, inputs finite
  return (short)(u >> 16);
}

__device__ inline void pollbar(unsigned* bar, unsigned target) {
  while (__hip_atomic_load(bar, __ATOMIC_RELAXED, __HIP_MEMORY_SCOPE_AGENT) < target)
    __builtin_amdgcn_s_sleep(2);
}
__device__ inline void arrive(unsigned* cnt, int grp, unsigned* bar, unsigned phase) {
  unsigned old = atomicAdd(&cnt[grp << 5], 1u);
  if (old == (phase << 5) - 1u) atomicAdd(bar, 1u);
}

// publish-index -> tag in {1,2,3}; 0 (memset state) never matches; buffer overwrite
// of index h is gated through the all-to-all at h+1, so a reader can never see h+6
// (same tag mod 3) while still expecting h.
__device__ inline unsigned tag_of(int h) { return (unsigned)(h % 3) + 1u; }

__global__ __launch_bounds__(NTHR, 4)   // 1 block/CU (LDS 148 KB also enforces this)
void sink_kernel(const float* __restrict__ X,
                 const float* __restrict__ Y,
                 float* __restrict__ out,
                 unsigned char* __restrict__ ws) {
  unsigned* barI = (unsigned*)ws;             // one-time init barrier
  unsigned* cntI = (unsigned*)(ws + 512);     // 8 groups x 128B
  unsigned* bGt  = (unsigned*)(ws + 8192);    // tagged g-bias (tag in low 2 bits)
  unsigned* bFt  = (unsigned*)(ws + 24576);   // tagged f-bias
  short* Xb = (short*)(ws + 65536);           // 4096x64 bf16
  short* Yb = Xb + NN * DD;

  const int tid  = threadIdx.x;
  const int blk  = blockIdx.x;
  const int wave = tid >> 6;
  const int lane = tid & 63;
  const int i0   = blk << 4;
  const int c0   = (wave << 4) + (lane & 15); // this thread's column slot (mod 256)

  __shared__ uint2 sgl[16][NTHR];             // S_g: all 16 tiles (128 KB)
  __shared__ unsigned bias_lds[NN];           // staged tagged bias (16 KB)
  __shared__ float red[NWAVE * 16];
  __shared__ float sh_xsq[16], sh_ysq[16];

  // ---- init: convert own 16 rows of BOTH matrices + row norms ----
  Xb[blk * NTHR + tid] = bf16_of(X[blk * NTHR + tid]);
  Yb[blk * NTHR + tid] = bf16_of(Y[blk * NTHR + tid]);
  {
    const int row = i0 + wave;
    float vx = X[row * DD + lane];
    float vy = Y[row * DD + lane];
    float sx = vx * vx, sy = vy * vy;
#pragma unroll
    for (int o = 1; o < 64; o <<= 1) { sx += __shfl_xor(sx, o); sy += __shfl_xor(sy, o); }
    if (lane == 0) { sh_xsq[wave] = 0.5f * sx; sh_ysq[wave] = 0.5f * sy; }
  }
  __syncthreads();
  if (tid == 0) {                             // one-time fenced barrier for Xb/Yb
    __threadfence();
    arrive(cntI, blk >> 5, barI, 1);
    pollbar(barI, 8u);
  }
  __syncthreads();

  // initial g-bias (g0=0), publish index h=0 -> tag 1
  if (tid < 16)
    LLC_STU(bGt + i0 + tid, (__float_as_uint(-sh_ysq[tid] * C2f) & ~3u) | 1u);

  // ---- build S_f (regs, 16 x uint2) and S_g (LDS tiles) ----
  uint2 sf[16];
  {
    const short* ap = Xb + ((i0 + (lane & 15)) << 6) + ((lane >> 4) << 3);
    short8 a0 = *(const short8*)ap;
    short8 a1 = *(const short8*)(ap + 32);
#pragma unroll
    for (int k = 0; k < 16; ++k) {
      const int jb = (wave << 4) + (k << 8);
      const short* bp = Yb + ((jb + (lane & 15)) << 6) + ((lane >> 4) << 3);
      short8 b0 = *(const short8*)bp;
      short8 b1 = *(const short8*)(bp + 32);
      f32x4 acc = {0.f, 0.f, 0.f, 0.f};
      acc = __builtin_amdgcn_mfma_f32_16x16x32_bf16(a0, b0, acc, 0, 0, 0);
      acc = __builtin_amdgcn_mfma_f32_16x16x32_bf16(a1, b1, acc, 0, 0, 0);
      sf[k].x = __builtin_bit_cast(unsigned, __builtin_amdgcn_cvt_pkrtz(acc[0], acc[1]));
      sf[k].y = __builtin_bit_cast(unsigned, __builtin_amdgcn_cvt_pkrtz(acc[2], acc[3]));
    }
  }
  {
    const short* ap = Yb + ((i0 + (lane & 15)) << 6) + ((lane >> 4) << 3);
    short8 a0 = *(const short8*)ap;
    short8 a1 = *(const short8*)(ap + 32);
#pragma unroll
    for (int k = 0; k < 16; ++k) {
      const int jb = (wave << 4) + (k << 8);
      const short* bp = Xb + ((jb + (lane & 15)) << 6) + ((lane >> 4) << 3);
      short8 b0 = *(const short8*)bp;
      short8 b1 = *(const short8*)(bp + 32);
      f32x4 acc = {0.f, 0.f, 0.f, 0.f};
      acc = __builtin_amdgcn_mfma_f32_16x16x32_bf16(a0, b0, acc, 0, 0, 0);
      acc = __builtin_amdgcn_mfma_f32_16x16x32_bf16(a1, b1, acc, 0, 0, 0);
      const unsigned w0 = __builtin_bit_cast(unsigned, __builtin_amdgcn_cvt_pkrtz(acc[0], acc[1]));
      const unsigned w1 = __builtin_bit_cast(unsigned, __builtin_amdgcn_cvt_pkrtz(acc[2], acc[3]));
      sgl[k][tid] = make_uint2(w0, w1);
    }
  }

  // publish indices: bGt gets h=0 (init) and h=2it+2 (g_it); bFt gets h=2it+1 (f_it).
  // f at it consumes bGt h=2it; g at it consumes bFt h=2it+1.
  for (int it = 0; it < ITERS; ++it) {
    const bool last = (it == ITERS - 1);

    // ================= f half-step (S_f in registers) =================
    {
      const unsigned tagIn  = tag_of(2 * it);
      const unsigned tagOut = tag_of(2 * it + 1);
      unsigned v[4];
#pragma unroll
      for (int q = 0; q < 4; ++q) v[q] = LLC_LDU(bGt + tid + (q << 10));
#pragma unroll
      for (int q = 0; q < 4; ++q) {
        while ((v[q] & 3u) != tagIn) {
          __builtin_amdgcn_s_sleep(1);
          v[q] = LLC_LDU(bGt + tid + (q << 10));
        }
        bias_lds[tid + (q << 10)] = v[q];
      }
      __syncthreads();
      float sum[4] = {0.f, 0.f, 0.f, 0.f};
#pragma unroll
      for (int k = 0; k < 16; ++k) {
        const float bb = __uint_as_float(bias_lds[c0 + (k << 8)]);
        half2v lo = __builtin_bit_cast(half2v, sf[k].x);
        half2v hi = __builtin_bit_cast(half2v, sf[k].y);
        sum[0] += __builtin_amdgcn_exp2f(__builtin_fmaf((float)lo[0], C2f, bb));
        sum[1] += __builtin_amdgcn_exp2f(__builtin_fmaf((float)lo[1], C2f, bb));
        sum[2] += __builtin_amdgcn_exp2f(__builtin_fmaf((float)hi[0], C2f, bb));
        sum[3] += __builtin_amdgcn_exp2f(__builtin_fmaf((float)hi[1], C2f, bb));
      }
#pragma unroll
      for (int o = 1; o <= 8; o <<= 1)
#pragma unroll
        for (int r = 0; r < 4; ++r) sum[r] += __shfl_xor(sum[r], o);
      if ((lane & 15) == 0)
#pragma unroll
        for (int r = 0; r < 4; ++r) red[wave * 16 + ((lane >> 4) << 2) + r] = sum[r];
      __syncthreads();
      if (tid < 16) {
        float total = 0.f;
#pragma unroll
        for (int w = 0; w < NWAVE; ++w) total += red[w * 16 + tid];
        const float pot = sh_xsq[tid] - EPSLN2f * __builtin_amdgcn_logf(total) + EPSLNNf;
        if (last) out[i0 + tid] = pot;
        LLC_STU(bFt + i0 + tid, (__float_as_uint((pot - sh_xsq[tid]) * C2f) & ~3u) | tagOut);
      }
      // no extra sync: g's stage-poll is gated on these publishes (incl. own 16)
    }

    // ================= g half-step (S_g in LDS) =================
    {
      const unsigned tagIn  = tag_of(2 * it + 1);
      const unsigned tagOut = tag_of(2 * it + 2);
      unsigned v[4];
#pragma unroll
      for (int q = 0; q < 4; ++q) v[q] = LLC_LDU(bFt + tid + (q << 10));
#pragma unroll
      for (int q = 0; q < 4; ++q) {
        while ((v[q] & 3u) != tagIn) {
          __builtin_amdgcn_s_sleep(1);
          v[q] = LLC_LDU(bFt + tid + (q << 10));
        }
        bias_lds[tid + (q << 10)] = v[q];
      }
      __syncthreads();
      float sum[4] = {0.f, 0.f, 0.f, 0.f};
#pragma unroll
      for (int k = 0; k < 16; ++k) {
        const float bb = __uint_as_float(bias_lds[c0 + (k << 8)]);
        const uint2 w = sgl[k][tid];
        half2v lo = __builtin_bit_cast(half2v, w.x);
        half2v hi = __builtin_bit_cast(half2v, w.y);
        sum[0] += __builtin_amdgcn_exp2f(__builtin_fmaf((float)lo[0], C2f, bb));
        sum[1] += __builtin_amdgcn_exp2f(__builtin_fmaf((float)lo[1], C2f, bb));
        sum[2] += __builtin_amdgcn_exp2f(__builtin_fmaf((float)hi[0], C2f, bb));
        sum[3] += __builtin_amdgcn_exp2f(__builtin_fmaf((float)hi[1], C2f, bb));
      }
#pragma unroll
      for (int o = 1; o <= 8; o <<= 1)
#pragma unroll
        for (int r = 0; r < 4; ++r) sum[r] += __shfl_xor(sum[r], o);
      if ((lane & 15) == 0)
#pragma unroll
        for (int r = 0; r < 4; ++r) red[wave * 16 + ((lane >> 4) << 2) + r] = sum[r];
      __syncthreads();
      if (tid < 16) {
        float total = 0.f;
#pragma unroll
        for (int w = 0; w < NWAVE; ++w) total += red[w * 16 + tid];
        const float pot = sh_ysq[tid] - EPSLN2f * __builtin_amdgcn_logf(total) + EPSLNNf;
        if (last) out[NN + i0 + tid] = pot;
        LLC_STU(bGt + i0 + tid, (__float_as_uint((pot - sh_ysq[tid]) * C2f) & ~3u) | tagOut);
      }
      // next f-stage is gated on these publishes
    }
  }
}

extern "C" void kernel_launch(void* const* d_in, const int* in_sizes, int n_in,
                              void* d_out, int out_size, void* d_ws, size_t ws_size,
                              hipStream_t stream) {
  const float* X = (const float*)d_in[0];
  const float* Y = (const float*)d_in[1];
  float* out = (float*)d_out;
  unsigned char* ws = (unsigned char*)d_ws;
  // zero init-barrier counters + both tagged-bias arrays (tag 0 = never-ready)
  hipMemsetAsync(d_ws, 0, 65536, stream);
  sink_kernel<<<dim3(NBLK), dim3(NTHR), 0, stream>>>(X, Y, out, ws);
}

// Round 13
// 481.164 us; speedup vs baseline: 4.8059x; 1.0256x over previous
//
#include <hip/hip_runtime.h>

#define NN 4096
#define DD 64
#define NBLK 256      // merged roles: block b owns f-rows and g-rows [16b, 16b+16)
#define NTHR 1024
#define NWAVE 16
#define ITERS 50

typedef __attribute__((ext_vector_type(8))) short short8;
typedef __attribute__((ext_vector_type(4))) float f32x4;
typedef _Float16 half2v __attribute__((ext_vector_type(2)));

#define C2f     0.4808983469629878f   /* 1/(eps*ln2), eps=3 */
#define EPSLN2f 2.0794415416798359f   /* eps*ln2 */
#define TWELVEf 12.0f                 /* log2(4096) = ln(n)/ln2 marginal term */

#define LLC_LDU(p)    __hip_atomic_load((p), __ATOMIC_RELAXED, __HIP_MEMORY_SCOPE_AGENT)
#define LLC_STU(p, v) __hip_atomic_store((p), (v), __ATOMIC_RELAXED, __HIP_MEMORY_SCOPE_AGENT)

__device__ inline short bf16_of(float f) {
  unsigned u = __float_as_uint(f);
  u += 0x7fffu + ((u >> 16) & 1u);   // RTNE, inputs finite
  return (short)(u >> 16);
}

__device__ inline void pollbar(unsigned* bar, unsigned target) {
  while (__hip_atomic_load(bar, __ATOMIC_RELAXED, __HIP_MEMORY_SCOPE_AGENT) < target)
    __builtin_amdgcn_s_sleep(2);
}
__device__ inline void arrive(unsigned* cnt, int grp, unsigned* bar, unsigned phase) {
  unsigned old = atomicAdd(&cnt[grp << 5], 1u);
  if (old == (phase << 5) - 1u) atomicAdd(bar, 1u);
}

// publish-index -> tag in {1,2,3}; 0 (memset state) never matches; buffer overwrite
// of index h is gated through the all-to-all at h+1, so a reader can never see a
// same-tag h+6 value while still expecting h.
__device__ inline unsigned tag_of(int h) { return (unsigned)(h % 3) + 1u; }

// Fused poll+stage with PARALLEL retry: all missing slots re-loaded back-to-back
// each round so their LLC latencies overlap (was serial per slot = up to 4x RTT).
__device__ __forceinline__ void poll_stage(unsigned* __restrict__ src, unsigned tagIn,
                                           unsigned* bias_lds, int tid) {
  unsigned v[4];
#pragma unroll
  for (int q = 0; q < 4; ++q) v[q] = LLC_LDU(src + tid + (q << 10));
  for (;;) {
    unsigned miss = 0;
#pragma unroll
    for (int q = 0; q < 4; ++q) miss |= ((v[q] & 3u) != tagIn) ? (1u << q) : 0u;
    if (!miss) break;
    __builtin_amdgcn_s_sleep(1);
#pragma unroll
    for (int q = 0; q < 4; ++q)
      if (miss & (1u << q)) v[q] = LLC_LDU(src + tid + (q << 10));
  }
#pragma unroll
  for (int q = 0; q < 4; ++q) bias_lds[tid + (q << 10)] = v[q];
}

__global__ __launch_bounds__(NTHR, 4)   // 1 block/CU (148 KB LDS also enforces this)
void sink_kernel(const float* __restrict__ X,
                 const float* __restrict__ Y,
                 float* __restrict__ out,
                 unsigned char* __restrict__ ws) {
  unsigned* barI = (unsigned*)ws;             // one-time init barrier
  unsigned* cntI = (unsigned*)(ws + 512);     // 8 groups x 128B
  unsigned* bGt  = (unsigned*)(ws + 8192);    // tagged g-bias (tag in low 2 bits)
  unsigned* bFt  = (unsigned*)(ws + 24576);   // tagged f-bias
  short* Xb = (short*)(ws + 65536);           // 4096x64 bf16
  short* Yb = Xb + NN * DD;

  const int tid  = threadIdx.x;
  const int blk  = blockIdx.x;
  const int wave = tid >> 6;
  const int lane = tid & 63;
  const int i0   = blk << 4;
  const int c0   = (wave << 4) + (lane & 15); // this thread's column slot (mod 256)

  __shared__ uint2 sgl[16][NTHR];             // S_g: all 16 tiles (128 KB)
  __shared__ unsigned bias_lds[NN];           // staged tagged bias (16 KB)
  __shared__ float red[16];                   // ds_add_f32 row accumulators
  __shared__ float sh_xsq[16], sh_ysq[16];

  // ---- init: convert own 16 rows of BOTH matrices + row norms ----
  Xb[blk * NTHR + tid] = bf16_of(X[blk * NTHR + tid]);
  Yb[blk * NTHR + tid] = bf16_of(Y[blk * NTHR + tid]);
  if (tid < 16) red[tid] = 0.f;
  {
    const int row = i0 + wave;
    float vx = X[row * DD + lane];
    float vy = Y[row * DD + lane];
    float sx = vx * vx, sy = vy * vy;
#pragma unroll
    for (int o = 1; o < 64; o <<= 1) { sx += __shfl_xor(sx, o); sy += __shfl_xor(sy, o); }
    if (lane == 0) { sh_xsq[wave] = 0.5f * sx; sh_ysq[wave] = 0.5f * sy; }
  }
  __syncthreads();
  if (tid == 0) {                             // one-time fenced barrier for Xb/Yb
    __threadfence();
    arrive(cntI, blk >> 5, barI, 1);
    pollbar(barI, 8u);
  }
  __syncthreads();

  // initial g-bias (g0=0), publish index h=0 -> tag 1
  if (tid < 16)
    LLC_STU(bGt + i0 + tid, (__float_as_uint(-sh_ysq[tid] * C2f) & ~3u) | 1u);

  // ---- build S_f (regs, 16 x uint2) and S_g (LDS tiles) ----
  uint2 sf[16];
  {
    const short* ap = Xb + ((i0 + (lane & 15)) << 6) + ((lane >> 4) << 3);
    short8 a0 = *(const short8*)ap;
    short8 a1 = *(const short8*)(ap + 32);
#pragma unroll
    for (int k = 0; k < 16; ++k) {
      const int jb = (wave << 4) + (k << 8);
      const short* bp = Yb + ((jb + (lane & 15)) << 6) + ((lane >> 4) << 3);
      short8 b0 = *(const short8*)bp;
      short8 b1 = *(const short8*)(bp + 32);
      f32x4 acc = {0.f, 0.f, 0.f, 0.f};
      acc = __builtin_amdgcn_mfma_f32_16x16x32_bf16(a0, b0, acc, 0, 0, 0);
      acc = __builtin_amdgcn_mfma_f32_16x16x32_bf16(a1, b1, acc, 0, 0, 0);
      sf[k].x = __builtin_bit_cast(unsigned, __builtin_amdgcn_cvt_pkrtz(acc[0], acc[1]));
      sf[k].y = __builtin_bit_cast(unsigned, __builtin_amdgcn_cvt_pkrtz(acc[2], acc[3]));
    }
  }
  {
    const short* ap = Yb + ((i0 + (lane & 15)) << 6) + ((lane >> 4) << 3);
    short8 a0 = *(const short8*)ap;
    short8 a1 = *(const short8*)(ap + 32);
#pragma unroll
    for (int k = 0; k < 16; ++k) {
      const int jb = (wave << 4) + (k << 8);
      const short* bp = Xb + ((jb + (lane & 15)) << 6) + ((lane >> 4) << 3);
      short8 b0 = *(const short8*)bp;
      short8 b1 = *(const short8*)(bp + 32);
      f32x4 acc = {0.f, 0.f, 0.f, 0.f};
      acc = __builtin_amdgcn_mfma_f32_16x16x32_bf16(a0, b0, acc, 0, 0, 0);
      acc = __builtin_amdgcn_mfma_f32_16x16x32_bf16(a1, b1, acc, 0, 0, 0);
      const unsigned w0 = __builtin_bit_cast(unsigned, __builtin_amdgcn_cvt_pkrtz(acc[0], acc[1]));
      const unsigned w1 = __builtin_bit_cast(unsigned, __builtin_amdgcn_cvt_pkrtz(acc[2], acc[3]));
      sgl[k][tid] = make_uint2(w0, w1);
    }
  }

  // publish indices: bGt gets h=0 (init) and h=2it+2 (g_it); bFt gets h=2it+1 (f_it).
  // f at it consumes bGt h=2it; g at it consumes bFt h=2it+1.
  // Published bias is EXACT: b = (pot - sq)*C2f = 12 - log2(Sigma).
  for (int it = 0; it < ITERS; ++it) {
    const bool last = (it == ITERS - 1);

    // ================= f half-step (S_f in registers) =================
    {
      const unsigned tagIn  = tag_of(2 * it);
      const unsigned tagOut = tag_of(2 * it + 1);
      poll_stage(bGt, tagIn, bias_lds, tid);
      __syncthreads();
      float sum[4] = {0.f, 0.f, 0.f, 0.f};
#pragma unroll
      for (int k = 0; k < 16; ++k) {
        const float bb = __uint_as_float(bias_lds[c0 + (k << 8)]);
        half2v lo = __builtin_bit_cast(half2v, sf[k].x);
        half2v hi = __builtin_bit_cast(half2v, sf[k].y);
        sum[0] += __builtin_amdgcn_exp2f(__builtin_fmaf((float)lo[0], C2f, bb));
        sum[1] += __builtin_amdgcn_exp2f(__builtin_fmaf((float)lo[1], C2f, bb));
        sum[2] += __builtin_amdgcn_exp2f(__builtin_fmaf((float)hi[0], C2f, bb));
        sum[3] += __builtin_amdgcn_exp2f(__builtin_fmaf((float)hi[1], C2f, bb));
      }
#pragma unroll
      for (int o = 1; o <= 8; o <<= 1)
#pragma unroll
        for (int r = 0; r < 4; ++r) sum[r] += __shfl_xor(sum[r], o);
      if ((lane & 15) == 0)
#pragma unroll
        for (int r = 0; r < 4; ++r) atomicAdd(&red[((lane >> 4) << 2) + r], sum[r]);
      __syncthreads();
      if (tid < 16) {
        const float bc = TWELVEf - __builtin_amdgcn_logf(red[tid]); // true bias
        LLC_STU(bFt + i0 + tid, (__float_as_uint(bc) & ~3u) | tagOut);
        red[tid] = 0.f;                                      // re-arm for g half
        if (last) out[i0 + tid] = sh_xsq[tid] + EPSLN2f * bc;
      }
      // no extra sync: g's stage-sync is gated on tid<16 arriving after the zero
    }

    // ================= g half-step (S_g in LDS) =================
    {
      const unsigned tagIn  = tag_of(2 * it + 1);
      const unsigned tagOut = tag_of(2 * it + 2);
      poll_stage(bFt, tagIn, bias_lds, tid);
      __syncthreads();
      float sum[4] = {0.f, 0.f, 0.f, 0.f};
#pragma unroll
      for (int k = 0; k < 16; ++k) {
        const float bb = __uint_as_float(bias_lds[c0 + (k << 8)]);
        const uint2 w = sgl[k][tid];
        half2v lo = __builtin_bit_cast(half2v, w.x);
        half2v hi = __builtin_bit_cast(half2v, w.y);
        sum[0] += __builtin_amdgcn_exp2f(__builtin_fmaf((float)lo[0], C2f, bb));
        sum[1] += __builtin_amdgcn_exp2f(__builtin_fmaf((float)lo[1], C2f, bb));
        sum[2] += __builtin_amdgcn_exp2f(__builtin_fmaf((float)hi[0], C2f, bb));
        sum[3] += __builtin_amdgcn_exp2f(__builtin_fmaf((float)hi[1], C2f, bb));
      }
#pragma unroll
      for (int o = 1; o <= 8; o <<= 1)
#pragma unroll
        for (int r = 0; r < 4; ++r) sum[r] += __shfl_xor(sum[r], o);
      if ((lane & 15) == 0)
#pragma unroll
        for (int r = 0; r < 4; ++r) atomicAdd(&red[((lane >> 4) << 2) + r], sum[r]);
      __syncthreads();
      if (tid < 16) {
        const float bc = TWELVEf - __builtin_amdgcn_logf(red[tid]); // true bias
        LLC_STU(bGt + i0 + tid, (__float_as_uint(bc) & ~3u) | tagOut);
        red[tid] = 0.f;                                      // re-arm for next f half
        if (last) out[NN + i0 + tid] = sh_ysq[tid] + EPSLN2f * bc;
      }
      // next f stage-sync gates on tid<16 as above
    }
  }
}

extern "C" void kernel_launch(void* const* d_in, const int* in_sizes, int n_in,
                              void* d_out, int out_size, void* d_ws, size_t ws_size,
                              hipStream_t stream) {
  const float* X = (const float*)d_in[0];
  const float* Y = (const float*)d_in[1];
  float* out = (float*)d_out;
  unsigned char* ws = (unsigned char*)d_ws;
  // zero init-barrier counters + both tagged-bias arrays (tag 0 = never-ready)
  hipMemsetAsync(d_ws, 0, 65536, stream);
  sink_kernel<<<dim3(NBLK), dim3(NTHR), 0, stream>>>(X, Y, out, ws);
}